// Round 13
// baseline (67.705 us; speedup 1.0000x reference)
//
#include <hip/hip_runtime.h>

#define DIM   256
#define CLS   512
#define NGF   32640          // packed strict-upper-triangle floats per class
#define NQ    8160           // NGF/4 float4 quads
#define NITER 5
#define PSH   72             // y part-slice stride in h16

typedef _Float16 h16;
typedef __attribute__((ext_vector_type(2))) _Float16 h16x2;

__device__ __forceinline__ float dot2f(unsigned a, unsigned b, float c) {
    return __builtin_amdgcn_fdot2(__builtin_bit_cast(h16x2, a),
                                  __builtin_bit_cast(h16x2, b), c, false);
}

__device__ __forceinline__ unsigned pkrtz(float lo, float hi) {
    return __builtin_bit_cast(unsigned, __builtin_amdgcn_cvt_pkrtz(lo, hi));
}

// barrier draining LDS only (vmcnt untouched)
__device__ __forceinline__ void bar_lds() {
    asm volatile("s_waitcnt lgkmcnt(0)\n\ts_barrier" ::: "memory");
}

// y[g] at part(g)*PSH + slot(g): part=(g>>4)&3, slot=((g>>6)<<4)|(g&15)
__device__ __forceinline__ int yaddr(int g) {
    return ((g >> 4) & 3) * PSH + (((g >> 6) << 4) | (g & 15));
}

// gather S[r][g] (f16, 0.5 baked in) from packed f16 triu at base
#define GATHER(BASE)                                                      \
    do {                                                                  \
        _Pragma("unroll")                                                 \
        for (int a_ = 0; a_ < 4; ++a_) {                                  \
            int g_  = 64 * a_ + 16 * p;                                   \
            int au_ = offr + g_;                                          \
            int al_ = ((g_ * (511 - g_)) >> 1) + r - g_ - 1;              \
            unsigned wacc_ = 0;                                           \
            _Pragma("unroll")                                             \
            for (int t_ = 0; t_ < 16; ++t_) {                             \
                int idx_ = (g_ < r) ? al_ : au_;                          \
                idx_ = idx_ < 0 ? 0 : idx_;                               \
                unsigned h_ = (BASE)[idx_];                               \
                h_ = (g_ < r) ? (h_ ^ 0x8000u) : h_;                      \
                h_ = (g_ == r) ? 0u : h_;                                 \
                if (t_ & 1) { wacc_ |= h_ << 16; sreg[(16*a_+t_) >> 1] = wacc_; } \
                else       { wacc_  = h_; }                               \
                ++au_;                                                    \
                al_ += 254 - g_;                                          \
                ++g_;                                                     \
            }                                                             \
        }                                                                 \
    } while (0)

#define ITERATE(XR, CC)                                                   \
    do {                                                                  \
        h16* ycur_ = sy0;                                                 \
        h16* ynxt_ = sy1;                                                 \
        for (int it_ = 0; it_ < NITER; ++it_) {                           \
            const uint4* yp_ = (const uint4*)(ycur_ + p * PSH);           \
            float a0_ = 0.f, a1_ = 0.f, a2_ = 0.f, a3_ = 0.f;             \
            _Pragma("unroll")                                             \
            for (int k_ = 0; k_ < 8; ++k_) {                              \
                uint4 yv_ = yp_[k_];                                      \
                a0_ = dot2f(sreg[4*k_+0], yv_.x, a0_);                    \
                a1_ = dot2f(sreg[4*k_+1], yv_.y, a1_);                    \
                a2_ = dot2f(sreg[4*k_+2], yv_.z, a2_);                    \
                a3_ = dot2f(sreg[4*k_+3], yv_.w, a3_);                    \
            }                                                             \
            float v_ = (a0_ + a1_) + (a2_ + a3_);                         \
            v_ += __shfl_xor(v_, 1);                                      \
            v_ += __shfl_xor(v_, 2);                                      \
            if (it_ < NITER - 1) {                                        \
                if (p == 0) ynxt_[wr] = (h16)((XR) - v_);                 \
                h16* t_ = ycur_; ycur_ = ynxt_; ynxt_ = t_;               \
                bar_lds();                                                \
            } else {                                                      \
                if (p == 0) out[(size_t)r * CLS + (CC)] = (XR) - 2.f * v_; \
            }                                                             \
        }                                                                 \
    } while (0)

__global__ void __launch_bounds__(1024)
cayley_kernel(const float* __restrict__ x, const float* __restrict__ W,
              float* __restrict__ out) {
    extern __shared__ char smem[];
    unsigned short* U0 = (unsigned short*)smem;            // 65536 B f16(0.5*W[cA])
    unsigned short* U1 = (unsigned short*)(smem + 65536);  // 65536 B f16(0.5*W[cB])
    h16* sy0 = (h16*)(smem + 131072);                      // 576 B
    h16* sy1 = sy0 + 4 * PSH;                              // 576 B

    const int tid  = threadIdx.x;
    const int r    = tid >> 2;       // row 0..255
    const int p    = tid & 3;        // part: owns columns {64a + 16p + t}
    const int cA   = blockIdx.x;
    const int cB   = blockIdx.x + 256;
    const int offr = (r * (511 - r)) / 2 - r - 1;
    const int wr   = yaddr(r);

    const float xrA = x[(size_t)r * CLS + cA];
    const float xrB = x[(size_t)r * CLS + cB];

    unsigned sreg[32];

    // ===== stage A: global f32 -> f16(0.5w) -> U0, coalesced =====
    {
        const float4* WA4 = (const float4*)(W + (size_t)cA * NGF);
        uint2* U2 = (uint2*)U0;
        #pragma unroll
        for (int k = 0; k < 8; ++k) {
            int q = tid + 1024 * k;
            float4 v = WA4[q < NQ ? q : 0];
            uint2 d;
            d.x = pkrtz(0.5f * v.x, 0.5f * v.y);
            d.y = pkrtz(0.5f * v.z, 0.5f * v.w);
            U2[q] = d;
        }
    }
    if (p == 0) sy0[wr] = (h16)xrA;
    __syncthreads();                       // U0 + y0(A) visible

    // ===== issue B prefetch (in flight during gather A) =====
    float4 bf[8];
    {
        const float4* WB4 = (const float4*)(W + (size_t)cB * NGF);
        #pragma unroll
        for (int k = 0; k < 8; ++k) {
            int q = tid + 1024 * k;
            bf[k] = WB4[q < NQ ? q : 0];
        }
    }

    GATHER(U0);                            // A's S-row slice -> sreg

    // convert B to packed f16 now (waits vmcnt; frees half the regs for iterate)
    unsigned wpk[16];
    #pragma unroll
    for (int k = 0; k < 8; ++k) {
        wpk[2*k]   = pkrtz(0.5f * bf[k].x, 0.5f * bf[k].y);
        wpk[2*k+1] = pkrtz(0.5f * bf[k].z, 0.5f * bf[k].w);
    }

    ITERATE(xrA, cA);                      // class A solve (writes out A)

    // ===== write B's staged f16 into U1 (region untouched by iterate) =====
    {
        uint2* U2 = (uint2*)U1;
        #pragma unroll
        for (int k = 0; k < 8; ++k) {
            int q = tid + 1024 * k;
            uint2 d; d.x = wpk[2*k]; d.y = wpk[2*k+1];
            U2[q] = d;
        }
    }
    __syncthreads();                       // all iterate-A reads done; U1 visible

    GATHER(U1);                            // B's S-row slice -> sreg
    if (p == 0) sy0[wr] = (h16)xrB;
    bar_lds();                             // y0(B) visible

    ITERATE(xrB, cB);                      // class B solve (writes out B)
}

extern "C" void kernel_launch(void* const* d_in, const int* in_sizes, int n_in,
                              void* d_out, int out_size, void* d_ws, size_t ws_size,
                              hipStream_t stream) {
    const float* x = (const float*)d_in[0];
    const float* W = (const float*)d_in[1];
    float* out = (float*)d_out;

    const size_t smem = 131072 + 2 * 4 * PSH * 2;   // 132224 B -> 1 block/CU
    hipFuncSetAttribute((const void*)cayley_kernel,
                        hipFuncAttributeMaxDynamicSharedMemorySize, (int)smem);
    hipLaunchKernelGGL(cayley_kernel, dim3(CLS / 2), dim3(1024), smem, stream, x, W, out);
}

// Round 14
// 50.938 us; speedup vs baseline: 1.3291x; 1.3291x over previous
//
#include <hip/hip_runtime.h>

#define DIM   256
#define CLS   512
#define NGF   32640          // packed strict-upper-triangle floats per class
#define NQ    8160           // NGF/4 float4 quads
#define NITER 5
#define PSH   72             // y part-slice stride in h16

typedef _Float16 h16;
typedef __attribute__((ext_vector_type(2))) _Float16 h16x2;

__device__ __forceinline__ float dot2f(unsigned a, unsigned b, float c) {
    return __builtin_amdgcn_fdot2(__builtin_bit_cast(h16x2, a),
                                  __builtin_bit_cast(h16x2, b), c, false);
}

__device__ __forceinline__ unsigned pkrtz(float lo, float hi) {
    return __builtin_bit_cast(unsigned, __builtin_amdgcn_cvt_pkrtz(lo, hi));
}

// barrier draining LDS only (vmcnt untouched)
__device__ __forceinline__ void bar_lds() {
    asm volatile("s_waitcnt lgkmcnt(0)\n\ts_barrier" ::: "memory");
}

// y[g] at part(g)*PSH + slot(g): part=(g>>4)&3, slot=((g>>6)<<4)|(g&15)
__device__ __forceinline__ int yaddr(int g) {
    return ((g >> 4) & 3) * PSH + (((g >> 6) << 4) | (g & 15));
}

// gather S[r][g] (f16, 0.5 baked in) from packed f16 triu at BASE -> sreg
#define GATHER(BASE)                                                      \
    do {                                                                  \
        _Pragma("unroll")                                                 \
        for (int a_ = 0; a_ < 4; ++a_) {                                  \
            int g_  = 64 * a_ + 16 * p;                                   \
            int au_ = offr + g_;                                          \
            int al_ = ((g_ * (511 - g_)) >> 1) + r - g_ - 1;              \
            unsigned wacc_ = 0;                                           \
            _Pragma("unroll")                                             \
            for (int t_ = 0; t_ < 16; ++t_) {                             \
                int idx_ = (g_ < r) ? al_ : au_;                          \
                idx_ = idx_ < 0 ? 0 : idx_;                               \
                unsigned h_ = (BASE)[idx_];                               \
                h_ = (g_ < r) ? (h_ ^ 0x8000u) : h_;                      \
                h_ = (g_ == r) ? 0u : h_;                                 \
                if (t_ & 1) { wacc_ |= h_ << 16; sreg[(16*a_+t_) >> 1] = wacc_; } \
                else       { wacc_  = h_; }                               \
                ++au_;                                                    \
                al_ += 254 - g_;                                          \
                ++g_;                                                     \
            }                                                             \
        }                                                                 \
    } while (0)

#define DOTS(V)                                                           \
    float V;                                                              \
    do {                                                                  \
        float a0_ = 0.f, a1_ = 0.f, a2_ = 0.f, a3_ = 0.f;                 \
        _Pragma("unroll")                                                 \
        for (int k_ = 0; k_ < 8; ++k_) {                                  \
            uint4 yv_ = yp[k_];                                           \
            a0_ = dot2f(sreg[4*k_+0], yv_.x, a0_);                        \
            a1_ = dot2f(sreg[4*k_+1], yv_.y, a1_);                        \
            a2_ = dot2f(sreg[4*k_+2], yv_.z, a2_);                        \
            a3_ = dot2f(sreg[4*k_+3], yv_.w, a3_);                        \
        }                                                                 \
        V = (a0_ + a1_) + (a2_ + a3_);                                    \
        V += __shfl_xor(V, 1);                                            \
        V += __shfl_xor(V, 2);                                            \
    } while (0)

__global__ void __launch_bounds__(1024)
cayley_kernel(const float* __restrict__ x, const float* __restrict__ W,
              float* __restrict__ out) {
    extern __shared__ char smem[];
    unsigned short* U0 = (unsigned short*)smem;            // 64 KB f16(0.5*W[cA])
    unsigned short* U1 = (unsigned short*)(smem + 65536);  // 64 KB f16(0.5*W[cB])
    h16* sy0 = (h16*)(smem + 131072);                      // 576 B
    h16* sy1 = sy0 + 4 * PSH;                              // 576 B

    const int tid  = threadIdx.x;
    const int r    = tid >> 2;       // row 0..255
    const int p    = tid & 3;        // part: owns columns {64a + 16p + t}
    const int cA   = blockIdx.x;
    const int cB   = blockIdx.x + 256;
    const int offr = (r * (511 - r)) / 2 - r - 1;
    const int wr   = yaddr(r);

    const float xrA = x[(size_t)r * CLS + cA];
    unsigned sreg[32];

    // ===== stage A: global f32 -> f16(0.5w) -> U0, coalesced =====
    {
        const float4* WA4 = (const float4*)(W + (size_t)cA * NGF);
        uint2* U2 = (uint2*)U0;
        #pragma unroll
        for (int k = 0; k < 8; ++k) {
            int q = tid + 1024 * k;
            float4 v = WA4[q < NQ ? q : 0];
            uint2 d;
            d.x = pkrtz(0.5f * v.x, 0.5f * v.y);
            d.y = pkrtz(0.5f * v.z, 0.5f * v.w);
            U2[q] = d;
        }
    }
    if (p == 0) sy0[wr] = (h16)xrA;
    __syncthreads();                        // U0 + y0(A) visible

    // ===== issue first 2 B-chunks (in flight during gather A) =====
    const float4* WB4 = (const float4*)(W + (size_t)cB * NGF);
    float4 bA = WB4[tid];                   // chunk 0 (tid+0*1024, < NQ always)
    float4 bB = WB4[tid + 1024];            // chunk 1

    GATHER(U0);                             // A's S-row slice -> sreg

    // ===== iterate A, with B staging woven in (2 chunks per iteration) =====
    {
        uint2* U1w = (uint2*)U1;
        #pragma unroll
        for (int it = 0; it < NITER; ++it) {
            const h16* ycur = (it & 1) ? sy1 : sy0;
            h16*       ynxt = (it & 1) ? sy0 : sy1;
            const uint4* yp = (const uint4*)(ycur + p * PSH);
            DOTS(v);
            if (it < NITER - 1) {
                if (p == 0) ynxt[wr] = (h16)(xrA - v);
            } else {
                if (p == 0) out[(size_t)r * CLS + cA] = xrA - 2.f * v;
            }
            if (it < 4) {                   // weave: convert+write chunks 2it,2it+1
                uint2 d0, d1;
                d0.x = pkrtz(0.5f * bA.x, 0.5f * bA.y);
                d0.y = pkrtz(0.5f * bA.z, 0.5f * bA.w);
                d1.x = pkrtz(0.5f * bB.x, 0.5f * bB.y);
                d1.y = pkrtz(0.5f * bB.z, 0.5f * bB.w);
                U1w[tid + 1024 * (2 * it)]     = d0;
                U1w[tid + 1024 * (2 * it + 1)] = d1;
                if (it < 3) {               // issue next 2 chunks
                    int qa = tid + 1024 * (2 * it + 2);
                    int qb = tid + 1024 * (2 * it + 3);
                    bA = WB4[qa < NQ ? qa : 0];
                    bB = WB4[qb < NQ ? qb : 0];
                }
            }
            if (it < NITER - 1) bar_lds();
        }
    }
    __syncthreads();                        // drains all; U1 visible; A y-reads done

    // ===== class B =====
    const float xrB = x[(size_t)r * CLS + cB];
    GATHER(U1);
    if (p == 0) sy0[wr] = (h16)xrB;
    bar_lds();                              // y0(B) visible

    {
        #pragma unroll
        for (int it = 0; it < NITER; ++it) {
            const h16* ycur = (it & 1) ? sy1 : sy0;
            h16*       ynxt = (it & 1) ? sy0 : sy1;
            const uint4* yp = (const uint4*)(ycur + p * PSH);
            DOTS(v);
            if (it < NITER - 1) {
                if (p == 0) ynxt[wr] = (h16)(xrB - v);
                bar_lds();
            } else {
                if (p == 0) out[(size_t)r * CLS + cB] = xrB - 2.f * v;
            }
        }
    }
}

extern "C" void kernel_launch(void* const* d_in, const int* in_sizes, int n_in,
                              void* d_out, int out_size, void* d_ws, size_t ws_size,
                              hipStream_t stream) {
    const float* x = (const float*)d_in[0];
    const float* W = (const float*)d_in[1];
    float* out = (float*)d_out;

    const size_t smem = 131072 + 2 * 4 * PSH * 2;   // 132224 B -> 1 block/CU
    hipFuncSetAttribute((const void*)cayley_kernel,
                        hipFuncAttributeMaxDynamicSharedMemorySize, (int)smem);
    hipLaunchKernelGGL(cayley_kernel, dim3(CLS / 2), dim3(1024), smem, stream, x, W, out);
}

// Round 15
// 47.244 us; speedup vs baseline: 1.4331x; 1.0782x over previous
//
#include <hip/hip_runtime.h>

#define DIM   256
#define CLS   512
#define NGF   32640          // packed strict-upper-triangle floats per class
#define NQ    8160           // NGF/4 float4 quads
#define NITER 5
#define PSH   72             // y part-slice stride in h16

typedef _Float16 h16;
typedef __attribute__((ext_vector_type(2))) _Float16 h16x2;

__device__ __forceinline__ float dot2f(unsigned a, unsigned b, float c) {
    return __builtin_amdgcn_fdot2(__builtin_bit_cast(h16x2, a),
                                  __builtin_bit_cast(h16x2, b), c, false);
}

__device__ __forceinline__ unsigned pkrtz(float lo, float hi) {
    return __builtin_bit_cast(unsigned, __builtin_amdgcn_cvt_pkrtz(lo, hi));
}

__device__ __forceinline__ uint2 cvt2(float4 v) {
    uint2 d;
    d.x = pkrtz(0.5f * v.x, 0.5f * v.y);
    d.y = pkrtz(0.5f * v.z, 0.5f * v.w);
    return d;
}

// barrier draining LDS only (vmcnt untouched)
__device__ __forceinline__ void bar_lds() {
    asm volatile("s_waitcnt lgkmcnt(0)\n\ts_barrier" ::: "memory");
}

// y[g] at part(g)*PSH + slot(g): part=(g>>4)&3, slot=((g>>6)<<4)|(g&15)
__device__ __forceinline__ int yaddr(int g) {
    return ((g >> 4) & 3) * PSH + (((g >> 6) << 4) | (g & 15));
}

// one 16-col gather chunk a_ -> sreg[8a..8a+7]
#define GCHUNK(BASE, A)                                                   \
    do {                                                                  \
        int g_  = 64 * (A) + 16 * p;                                      \
        int au_ = offr + g_;                                              \
        int al_ = ((g_ * (511 - g_)) >> 1) + r - g_ - 1;                  \
        unsigned wacc_ = 0;                                               \
        _Pragma("unroll")                                                 \
        for (int t_ = 0; t_ < 16; ++t_) {                                 \
            int idx_ = (g_ < r) ? al_ : au_;                              \
            idx_ = idx_ < 0 ? 0 : idx_;                                   \
            unsigned h_ = (BASE)[idx_];                                   \
            h_ = (g_ < r) ? (h_ ^ 0x8000u) : h_;                          \
            h_ = (g_ == r) ? 0u : h_;                                     \
            if (t_ & 1) { wacc_ |= h_ << 16; sreg[(16*(A)+t_) >> 1] = wacc_; } \
            else       { wacc_  = h_; }                                   \
            ++au_;                                                        \
            al_ += 254 - g_;                                              \
            ++g_;                                                         \
        }                                                                 \
    } while (0)

#define DOTS(V)                                                           \
    float V;                                                              \
    do {                                                                  \
        float a0_ = 0.f, a1_ = 0.f, a2_ = 0.f, a3_ = 0.f;                 \
        _Pragma("unroll")                                                 \
        for (int k_ = 0; k_ < 8; ++k_) {                                  \
            uint4 yv_ = yp[k_];                                           \
            a0_ = dot2f(sreg[4*k_+0], yv_.x, a0_);                        \
            a1_ = dot2f(sreg[4*k_+1], yv_.y, a1_);                        \
            a2_ = dot2f(sreg[4*k_+2], yv_.z, a2_);                        \
            a3_ = dot2f(sreg[4*k_+3], yv_.w, a3_);                        \
        }                                                                 \
        V = (a0_ + a1_) + (a2_ + a3_);                                    \
        V += __shfl_xor(V, 1);                                            \
        V += __shfl_xor(V, 2);                                            \
    } while (0)

__global__ void __launch_bounds__(1024)
cayley_kernel(const float* __restrict__ x, const float* __restrict__ W,
              float* __restrict__ out) {
    extern __shared__ char smem[];
    unsigned short* U  = (unsigned short*)smem;        // 65536 B f16(0.5*W), reused A->B
    uint2*          U2 = (uint2*)smem;
    h16* sy0 = (h16*)(smem + 65536);                   // 576 B
    h16* sy1 = sy0 + 4 * PSH;                          // 576 B

    const int tid  = threadIdx.x;
    const int r    = tid >> 2;       // row 0..255
    const int p    = tid & 3;        // part: owns columns {64a + 16p + t}
    const int cA   = blockIdx.x;
    const int cB   = blockIdx.x + 256;
    const int offr = (r * (511 - r)) / 2 - r - 1;
    const int wr   = yaddr(r);

    const float xrA = x[(size_t)r * CLS + cA];
    const float xrB = x[(size_t)r * CLS + cB];
    unsigned sreg[32];

    // ===== stage A: global f32 -> f16(0.5w) -> U, coalesced =====
    {
        const float4* WA4 = (const float4*)(W + (size_t)cA * NGF);
        #pragma unroll
        for (int k = 0; k < 8; ++k) {
            int q = tid + 1024 * k;
            U2[q] = cvt2(WA4[q < NQ ? q : 0]);
        }
    }
    if (p == 0) sy0[wr] = (h16)xrA;
    __syncthreads();                        // U(A) + y0(A) visible

    // ===== gather A, weaving B chunks 0-3 (depth-1: one float4 in flight) =====
    const float4* WB4 = (const float4*)(W + (size_t)cB * NGF);
    float4 inf = WB4[tid];                  // B chunk 0
    unsigned wpk[8];                        // B chunks 0-3, converted

    GCHUNK(U, 0);
    { uint2 d = cvt2(inf); wpk[0] = d.x; wpk[1] = d.y; inf = WB4[tid + 1024]; }
    GCHUNK(U, 1);
    { uint2 d = cvt2(inf); wpk[2] = d.x; wpk[3] = d.y; inf = WB4[tid + 2048]; }
    GCHUNK(U, 2);
    { uint2 d = cvt2(inf); wpk[4] = d.x; wpk[5] = d.y; inf = WB4[tid + 3072]; }
    GCHUNK(U, 3);
    { uint2 d = cvt2(inf); wpk[6] = d.x; wpk[7] = d.y; inf = WB4[tid + 4096]; }

    __syncthreads();                        // all gathers done -> U is dead

    // B chunks 0-3 from wpk -> U (frees 8 regs)
    #pragma unroll
    for (int k = 0; k < 4; ++k) {
        uint2 d; d.x = wpk[2*k]; d.y = wpk[2*k+1];
        U2[tid + 1024 * k] = d;
    }

    // ===== iterate A, weaving B chunks 4-7 (convert + write directly to U) =====
    {
        #pragma unroll
        for (int it = 0; it < NITER; ++it) {
            const h16* ycur = (it & 1) ? sy1 : sy0;
            h16*       ynxt = (it & 1) ? sy0 : sy1;
            const uint4* yp = (const uint4*)(ycur + p * PSH);
            DOTS(v);
            if (it < NITER - 1) {
                if (p == 0) ynxt[wr] = (h16)(xrA - v);
            } else {
                if (p == 0) out[(size_t)r * CLS + cA] = xrA - 2.f * v;
            }
            if (it < 4) {                   // weave slot: B chunk 4+it
                int qc = tid + 1024 * (4 + it);
                if (qc < NQ || it < 3) U2[qc] = cvt2(inf);
                if (it < 3) {
                    int qn = tid + 1024 * (5 + it);
                    inf = WB4[qn < NQ ? qn : 0];
                }
            }
            if (it < NITER - 1) bar_lds();
        }
    }
    __syncthreads();                        // U(B) complete; A y-reads done

    // ===== class B =====
    GCHUNK(U, 0); GCHUNK(U, 1); GCHUNK(U, 2); GCHUNK(U, 3);
    if (p == 0) sy0[wr] = (h16)xrB;
    bar_lds();                              // y0(B) visible

    {
        #pragma unroll
        for (int it = 0; it < NITER; ++it) {
            const h16* ycur = (it & 1) ? sy1 : sy0;
            h16*       ynxt = (it & 1) ? sy0 : sy1;
            const uint4* yp = (const uint4*)(ycur + p * PSH);
            DOTS(v);
            if (it < NITER - 1) {
                if (p == 0) ynxt[wr] = (h16)(xrB - v);
                bar_lds();
            } else {
                if (p == 0) out[(size_t)r * CLS + cB] = xrB - 2.f * v;
            }
        }
    }
}

extern "C" void kernel_launch(void* const* d_in, const int* in_sizes, int n_in,
                              void* d_out, int out_size, void* d_ws, size_t ws_size,
                              hipStream_t stream) {
    const float* x = (const float*)d_in[0];
    const float* W = (const float*)d_in[1];
    float* out = (float*)d_out;

    const size_t smem = 65536 + 2 * 4 * PSH * 2;   // 66688 B
    hipFuncSetAttribute((const void*)cayley_kernel,
                        hipFuncAttributeMaxDynamicSharedMemorySize, (int)smem);
    hipLaunchKernelGGL(cayley_kernel, dim3(CLS / 2), dim3(1024), smem, stream, x, W, out);
}